// Round 1
// baseline (19586.586 us; speedup 1.0000x reference)
//
#include <hip/hip_runtime.h>
#include <math.h>

#define DIMD  300   // token embedding dim / encoder input dim
#define NHEAD 15
#define DKK   20
#define DVV   20
#define HDIM  300   // NHEAD*DVV
#define ADIM  200
#define BATCH 128
#define NHIS  50
#define NCAND 5
#define LNEWS 30

// One block = one encoder instance (position p, batch b).
// Per head: stage weight slice [300][20] into WS, compute q/k/v slices,
// scores (->WS), softmax, ctx accumulation. Then additive-attention pooling.
template<int LQ, bool GATHER>
__global__ __launch_bounds__(256)
void encode_kernel(const float* __restrict__ src,    // GATHER: emb [V,300]; else news_enc [B,50,300]
                   const int*   __restrict__ tokens, // [B,P,LQ] (GATHER only)
                   const float* __restrict__ Wq,     // [P,300,300]
                   const float* __restrict__ Wk,     // [P,300,300]
                   const float* __restrict__ Wv,     // [P,300,300]
                   const float* __restrict__ Wp,     // [P,300,200]
                   const float* __restrict__ bp,     // [P,200]
                   const float* __restrict__ qv,     // [P,200]
                   float* __restrict__ out,          // [B,P,300]
                   int P)
{
    __shared__ float X[LQ][DIMD];     // input rows
    __shared__ float CTX[LQ][HDIM];   // MHSA output
    __shared__ float QH[LQ][DKK];
    __shared__ float KH[LQ][DKK];
    __shared__ float VH[LQ][DVV];
    __shared__ float WS[DIMD * DKK];  // 6000 f32: weight slice / scores / pool partials
    __shared__ float SL[64];          // pooled attention logits/weights

    const int t   = threadIdx.x;
    const int blk = blockIdx.x;
    const int p   = blk / BATCH;      // p-major: co-resident blocks share weights
    const int b   = blk % BATCH;

    const float* Wq_p = Wq + (size_t)p * DIMD * HDIM;
    const float* Wk_p = Wk + (size_t)p * DIMD * HDIM;
    const float* Wv_p = Wv + (size_t)p * DIMD * HDIM;
    const float* Wp_p = Wp + (size_t)p * DIMD * ADIM;
    const float* bp_p = bp + (size_t)p * ADIM;
    const float* qv_p = qv + (size_t)p * ADIM;

    // ---- load X ----
    if (GATHER) {
        for (int i = t; i < LQ * DIMD; i += 256) {
            int l = i / DIMD, d = i - l * DIMD;
            int tok = tokens[((size_t)b * P + p) * LQ + l];
            X[l][d] = src[(size_t)tok * DIMD + d];
        }
    } else {
        for (int i = t; i < LQ * DIMD; i += 256) {
            int l = i / DIMD, d = i - l * DIMD;
            X[l][d] = src[((size_t)b * LQ + l) * DIMD + d];
        }
    }
    __syncthreads();

    // ---- per-head MHSA ----
    for (int h = 0; h < NHEAD; ++h) {
        // Q
        for (int i = t; i < DIMD * DKK; i += 256)
            WS[i] = Wq_p[(i / DKK) * HDIM + h * DKK + (i % DKK)];
        __syncthreads();
        for (int i = t; i < LQ * DKK; i += 256) {
            int l = i / DKK, j = i - l * DKK;
            float a0 = 0, a1 = 0, a2 = 0, a3 = 0;
            for (int d = 0; d < DIMD; d += 4) {
                a0 = fmaf(X[l][d + 0], WS[(d + 0) * DKK + j], a0);
                a1 = fmaf(X[l][d + 1], WS[(d + 1) * DKK + j], a1);
                a2 = fmaf(X[l][d + 2], WS[(d + 2) * DKK + j], a2);
                a3 = fmaf(X[l][d + 3], WS[(d + 3) * DKK + j], a3);
            }
            QH[l][j] = (a0 + a1) + (a2 + a3);
        }
        __syncthreads();
        // K
        for (int i = t; i < DIMD * DKK; i += 256)
            WS[i] = Wk_p[(i / DKK) * HDIM + h * DKK + (i % DKK)];
        __syncthreads();
        for (int i = t; i < LQ * DKK; i += 256) {
            int l = i / DKK, j = i - l * DKK;
            float a0 = 0, a1 = 0, a2 = 0, a3 = 0;
            for (int d = 0; d < DIMD; d += 4) {
                a0 = fmaf(X[l][d + 0], WS[(d + 0) * DKK + j], a0);
                a1 = fmaf(X[l][d + 1], WS[(d + 1) * DKK + j], a1);
                a2 = fmaf(X[l][d + 2], WS[(d + 2) * DKK + j], a2);
                a3 = fmaf(X[l][d + 3], WS[(d + 3) * DKK + j], a3);
            }
            KH[l][j] = (a0 + a1) + (a2 + a3);
        }
        __syncthreads();
        // V
        for (int i = t; i < DIMD * DVV; i += 256)
            WS[i] = Wv_p[(i / DVV) * HDIM + h * DVV + (i % DVV)];
        __syncthreads();
        for (int i = t; i < LQ * DVV; i += 256) {
            int l = i / DVV, j = i - l * DVV;
            float a0 = 0, a1 = 0, a2 = 0, a3 = 0;
            for (int d = 0; d < DIMD; d += 4) {
                a0 = fmaf(X[l][d + 0], WS[(d + 0) * DVV + j], a0);
                a1 = fmaf(X[l][d + 1], WS[(d + 1) * DVV + j], a1);
                a2 = fmaf(X[l][d + 2], WS[(d + 2) * DVV + j], a2);
                a3 = fmaf(X[l][d + 3], WS[(d + 3) * DVV + j], a3);
            }
            VH[l][j] = (a0 + a1) + (a2 + a3);
        }
        __syncthreads();
        // scores = q.k^T / sqrt(DK)  -> WS[LQ*LQ]
        for (int i = t; i < LQ * LQ; i += 256) {
            int l = i / LQ, m = i - l * LQ;
            float s = 0;
            #pragma unroll
            for (int j = 0; j < DKK; ++j)
                s = fmaf(QH[l][j], KH[m][j], s);
            WS[i] = s * 0.22360679774997896f;  // 1/sqrt(20)
        }
        __syncthreads();
        // row softmax
        for (int l = t; l < LQ; l += 256) {
            float mx = -1e30f;
            for (int m = 0; m < LQ; ++m) mx = fmaxf(mx, WS[l * LQ + m]);
            float sum = 0;
            for (int m = 0; m < LQ; ++m) {
                float e = __expf(WS[l * LQ + m] - mx);
                WS[l * LQ + m] = e;
                sum += e;
            }
            float inv = 1.0f / sum;
            for (int m = 0; m < LQ; ++m) WS[l * LQ + m] *= inv;
        }
        __syncthreads();
        // ctx[l, h*DVV+j] = sum_m attn[l,m] * v[m,j]
        for (int i = t; i < LQ * DVV; i += 256) {
            int l = i / DVV, j = i - l * DVV;
            float c = 0;
            for (int m = 0; m < LQ; ++m)
                c = fmaf(WS[l * LQ + m], VH[m][j], c);
            CTX[l][h * DVV + j] = c;
        }
        __syncthreads();
    }

    // ---- additive attention pooling ----
    constexpr int F = (LQ <= 32) ? 8 : 4;   // LQ*F <= 256
    {
        int l = t / F, f = t - (t / F) * F;
        float part = 0.0f;
        if (l < LQ) {
            for (int a = f; a < ADIM; a += F) {
                float s0 = 0, s1 = 0, s2 = 0, s3 = 0;
                for (int c = 0; c < HDIM; c += 4) {
                    s0 = fmaf(CTX[l][c + 0], Wp_p[(c + 0) * ADIM + a], s0);
                    s1 = fmaf(CTX[l][c + 1], Wp_p[(c + 1) * ADIM + a], s1);
                    s2 = fmaf(CTX[l][c + 2], Wp_p[(c + 2) * ADIM + a], s2);
                    s3 = fmaf(CTX[l][c + 3], Wp_p[(c + 3) * ADIM + a], s3);
                }
                float tv = tanhf((s0 + s1) + (s2 + s3) + bp_p[a]);
                part = fmaf(tv, qv_p[a], part);
            }
        }
        __syncthreads();
        if (l < LQ) WS[l * F + f] = part;
        __syncthreads();
        if (t < LQ) {
            float s = 0;
            for (int f2 = 0; f2 < F; ++f2) s += WS[t * F + f2];
            SL[t] = s;
        }
        __syncthreads();
        if (t == 0) {
            float mx = -1e30f;
            for (int l2 = 0; l2 < LQ; ++l2) mx = fmaxf(mx, SL[l2]);
            float sum = 0;
            for (int l2 = 0; l2 < LQ; ++l2) {
                float e = __expf(SL[l2] - mx);
                SL[l2] = e;
                sum += e;
            }
            float inv = 1.0f / sum;
            for (int l2 = 0; l2 < LQ; ++l2) SL[l2] *= inv;
        }
        __syncthreads();
    }
    // out[c] = sum_l a[l] * ctx[l][c]
    for (int c = t; c < HDIM; c += 256) {
        float o = 0;
        for (int l2 = 0; l2 < LQ; ++l2)
            o = fmaf(SL[l2], CTX[l2][c], o);
        out[((size_t)b * P + p) * HDIM + c] = o;
    }
}

// scores[b,c] = user_rep[b] . cand_enc[b,c]; softmax over c
__global__ __launch_bounds__(320)
void score_kernel(const float* __restrict__ user_rep, // [B,300]
                  const float* __restrict__ cand_enc, // [B,5,300]
                  float* __restrict__ out)            // [B,5]
{
    __shared__ float sc[NCAND];
    int b = blockIdx.x;
    int w = threadIdx.x >> 6;       // wave id = candidate
    int lane = threadIdx.x & 63;
    float partial = 0;
    for (int d = lane; d < HDIM; d += 64)
        partial = fmaf(user_rep[b * HDIM + d], cand_enc[((size_t)b * NCAND + w) * HDIM + d], partial);
    for (int off = 32; off > 0; off >>= 1)
        partial += __shfl_down(partial, off, 64);
    if (lane == 0) sc[w] = partial;
    __syncthreads();
    if (threadIdx.x == 0) {
        float mx = -1e30f;
        for (int c = 0; c < NCAND; ++c) mx = fmaxf(mx, sc[c]);
        float sum = 0;
        float e[NCAND];
        for (int c = 0; c < NCAND; ++c) { e[c] = __expf(sc[c] - mx); sum += e[c]; }
        float inv = 1.0f / sum;
        for (int c = 0; c < NCAND; ++c) out[b * NCAND + c] = e[c] * inv;
    }
}

extern "C" void kernel_launch(void* const* d_in, const int* in_sizes, int n_in,
                              void* d_out, int out_size, void* d_ws, size_t ws_size,
                              hipStream_t stream) {
    const int*   news_input = (const int*)d_in[0];   // [B,50,30]
    const int*   candidates = (const int*)d_in[1];   // [B,5,30]
    const float* emb        = (const float*)d_in[2]; // [V,300]
    const float* his_Wq  = (const float*)d_in[3];
    const float* his_Wk  = (const float*)d_in[4];
    const float* his_Wv  = (const float*)d_in[5];
    const float* his_Wp  = (const float*)d_in[6];
    const float* his_bp  = (const float*)d_in[7];
    const float* his_qv  = (const float*)d_in[8];
    const float* cand_Wq = (const float*)d_in[9];
    const float* cand_Wk = (const float*)d_in[10];
    const float* cand_Wv = (const float*)d_in[11];
    const float* cand_Wp = (const float*)d_in[12];
    const float* cand_bp = (const float*)d_in[13];
    const float* cand_qv = (const float*)d_in[14];
    const float* usr_Wq  = (const float*)d_in[15];
    const float* usr_Wk  = (const float*)d_in[16];
    const float* usr_Wv  = (const float*)d_in[17];
    const float* usr_Wp  = (const float*)d_in[18];
    const float* usr_bp  = (const float*)d_in[19];
    const float* usr_qv  = (const float*)d_in[20];

    float* out = (float*)d_out;

    float* news_enc = (float*)d_ws;                        // [B,50,300]
    float* cand_enc = news_enc + BATCH * NHIS * HDIM;      // [B,5,300]
    float* user_rep = cand_enc + BATCH * NCAND * HDIM;     // [B,300]

    encode_kernel<LNEWS, true><<<NHIS * BATCH, 256, 0, stream>>>(
        emb, news_input, his_Wq, his_Wk, his_Wv, his_Wp, his_bp, his_qv, news_enc, NHIS);
    encode_kernel<LNEWS, true><<<NCAND * BATCH, 256, 0, stream>>>(
        emb, candidates, cand_Wq, cand_Wk, cand_Wv, cand_Wp, cand_bp, cand_qv, cand_enc, NCAND);
    encode_kernel<NHIS, false><<<BATCH, 256, 0, stream>>>(
        news_enc, nullptr, usr_Wq, usr_Wk, usr_Wv, usr_Wp, usr_bp, usr_qv, user_rep, 1);
    score_kernel<<<BATCH, 320, 0, stream>>>(user_rep, cand_enc, out);
}

// Round 2
// 2006.419 us; speedup vs baseline: 9.7620x; 9.7620x over previous
//
#include <hip/hip_runtime.h>
#include <math.h>

typedef __attribute__((ext_vector_type(8))) short short8;
typedef __attribute__((ext_vector_type(4))) float f32x4;

#define BATCH 128
#define NHIS  50
#define NCAND 5
#define KP    320   // padded K stride for transposed weights (elems)
#define XS    328   // X/CTX LDS row stride (elems) -> 656B rows, 16B aligned, bank-spread
#define QS    480   // Q/K LDS row stride: 15 heads * 32
#define NQKV  912   // padded N for [Wq|Wk|Wv]
#define NWP   208   // padded N for Wp
#define SCALE 0.22360679774997896f  // 1/sqrt(20)

__device__ __forceinline__ ushort f2bf(float f) {
    union { float f; unsigned u; } v; v.f = f;
    return (ushort)((v.u + 0x7fffu + ((v.u >> 16) & 1u)) >> 16);
}
__device__ __forceinline__ float bf2f(ushort u) {
    union { float f; unsigned u; } v; v.u = ((unsigned)u) << 16;
    return v.f;
}

// ---------- weight prep: W[k][n] fp32 -> WT[p][n][k] bf16, zero-padded ----------
__global__ void prep_qkv(const float* __restrict__ Wq, const float* __restrict__ Wk,
                         const float* __restrict__ Wv, ushort* __restrict__ dst, int P) {
    size_t i = (size_t)blockIdx.x * 256 + threadIdx.x;
    size_t total = (size_t)P * NQKV * KP;
    if (i >= total) return;
    int k = (int)(i % KP);
    int n = (int)((i / KP) % NQKV);
    int p = (int)(i / ((size_t)KP * NQKV));
    float v = 0.f;
    if (k < 300 && n < 900) {
        const float* W = (n < 300) ? Wq : (n < 600 ? Wk : Wv);
        int nn = n % 300;
        v = W[((size_t)p * 300 + k) * 300 + nn];
    }
    dst[i] = f2bf(v);
}

__global__ void prep_wp(const float* __restrict__ Wp, ushort* __restrict__ dst, int P) {
    size_t i = (size_t)blockIdx.x * 256 + threadIdx.x;
    size_t total = (size_t)P * NWP * KP;
    if (i >= total) return;
    int k = (int)(i % KP);
    int a = (int)((i / KP) % NWP);
    int p = (int)(i / ((size_t)KP * NWP));
    float v = 0.f;
    if (k < 300 && a < 200) v = Wp[((size_t)p * 300 + k) * 200 + a];
    dst[i] = f2bf(v);
}

// ---------- fused MFMA encoder, L=30 (news / cand), heads parallel over waves ----------
// MFMA 16x16x32 bf16 layouts (gfx950): A: lane(g=l>>4,r=l&15) holds A[r][8g+i];
// B: holds B[8g+i][r]; C/D: reg j = C[4g+j][r].
__global__ __launch_bounds__(512, 1)
void encode30(const float* __restrict__ emb, const int* __restrict__ tokens,
              const ushort* __restrict__ wt_qkv, const ushort* __restrict__ wt_wp,
              const float* __restrict__ bp, const float* __restrict__ qv,
              float* __restrict__ out, int P)
{
    __shared__ ushort Xb[32 * XS];        // 20,992 B; reused as CTX (bf16) after QKV
    __shared__ ushort Qb[32 * QS];        // 30,720 B  [row][h*32+j] (j<20 valid)
    __shared__ ushort Kb[32 * QS];        // 30,720 B
    __shared__ ushort VT[15 * 32 * 32];   // 30,720 B  [h][vj][m]
    __shared__ float  SC[8 * 32 * 32];    // 32,768 B  per-wave scores
    __shared__ ushort Pb[8 * 32 * 32];    // 16,384 B  per-wave P (bf16)
    __shared__ float  SL[64];             // 256 B     pool logits
    // total 162,560 B <= 163,840

    const int tid  = threadIdx.x;
    const int wave = tid >> 6;
    const int lane = tid & 63;
    const int r = lane & 15, g = lane >> 4;
    const int p = blockIdx.x / BATCH;     // p-major: co-resident blocks share weights (L2)
    const int b = blockIdx.x % BATCH;

    // zero LDS (pads must be 0)
    for (int i = tid; i < 32 * XS; i += 512) Xb[i] = 0;
    for (int i = tid; i < 32 * QS; i += 512) { Qb[i] = 0; Kb[i] = 0; }
    for (int i = tid; i < 15 * 1024; i += 512) VT[i] = 0;
    for (int i = tid; i < 8 * 1024; i += 512) Pb[i] = 0;
    if (tid < 64) SL[tid] = 0.f;
    __syncthreads();

    // gather X -> bf16
    const int* trow = tokens + ((size_t)b * P + p) * 30;
    for (int i = tid; i < 30 * 300; i += 512) {
        int l = i / 300, d = i - l * 300;
        Xb[l * XS + d] = f2bf(emb[(size_t)trow[l] * 300 + d]);
    }
    __syncthreads();

    // ---- QKV projection: [32 x 320] x [320 x 912] ----
    const ushort* wq = wt_qkv + (size_t)p * NQKV * KP;
    for (int tile = wave; tile < 114; tile += 8) {     // 57 nt x 2 mt
        int nt = tile >> 1, mt = tile & 1;
        f32x4 acc = {0.f, 0.f, 0.f, 0.f};
        const ushort* wrow = wq + (size_t)(nt * 16 + r) * KP;
        const ushort* xrow = &Xb[(mt * 16 + r) * XS];
        #pragma unroll
        for (int ks = 0; ks < 10; ++ks) {
            short8 a  = *(const short8*)(xrow + 32 * ks + 16 * g / 2 + 8 * g - 8 * g); // see below
            a = *(const short8*)(xrow + 32 * ks + 8 * g);
            short8 bb = *(const short8*)(wrow + 32 * ks + 8 * g);
            acc = __builtin_amdgcn_mfma_f32_16x16x32_bf16(a, bb, acc, 0, 0, 0);
        }
        int n = nt * 16 + r;
        if (n < 900) {
            int seg = (n >= 600) ? 2 : (n >= 300 ? 1 : 0);
            int nn = n - seg * 300;
            int h = nn / 20, jj = nn - h * 20;
            #pragma unroll
            for (int j = 0; j < 4; ++j) {
                int row = mt * 16 + 4 * g + j;
                ushort v = f2bf(acc[j]);
                if (seg == 0)      Qb[row * QS + h * 32 + jj] = v;
                else if (seg == 1) Kb[row * QS + h * 32 + jj] = v;
                else               VT[h * 1024 + jj * 32 + row] = v;
            }
        }
    }
    __syncthreads();

    // X dead; zero CTX region
    for (int i = tid; i < 32 * XS; i += 512) Xb[i] = 0;
    __syncthreads();

    // ---- attention: heads across waves, wave-private SC/Pb (no barriers needed) ----
    ushort* ctx = Xb;
    for (int hp = 0; hp < 2; ++hp) {
        int head = wave + 8 * hp;
        if (head < 15) {
            float*  sc = &SC[wave * 1024];
            ushort* pb = &Pb[wave * 1024];
            #pragma unroll
            for (int mt = 0; mt < 2; ++mt)
            #pragma unroll
            for (int nt = 0; nt < 2; ++nt) {
                short8 a  = *(const short8*)&Qb[(mt * 16 + r) * QS + head * 32 + 8 * g];
                short8 bb = *(const short8*)&Kb[(nt * 16 + r) * QS + head * 32 + 8 * g];
                f32x4 acc = {0.f, 0.f, 0.f, 0.f};
                acc = __builtin_amdgcn_mfma_f32_16x16x32_bf16(a, bb, acc, 0, 0, 0);
                #pragma unroll
                for (int j = 0; j < 4; ++j)
                    sc[(mt * 16 + 4 * g + j) * 32 + nt * 16 + r] = acc[j] * SCALE;
            }
            if (lane < 30) {  // row softmax (wave-internal RAW: in-order LDS pipe)
                float* row = &sc[lane * 32];
                float mx = -1e30f;
                #pragma unroll
                for (int m = 0; m < 30; ++m) mx = fmaxf(mx, row[m]);
                float ev[30]; float sum = 0.f;
                #pragma unroll
                for (int m = 0; m < 30; ++m) { ev[m] = __expf(row[m] - mx); sum += ev[m]; }
                float inv = 1.0f / sum;
                ushort* prow = &pb[lane * 32];
                #pragma unroll
                for (int m = 0; m < 30; ++m) prow[m] = f2bf(ev[m] * inv);
                prow[30] = 0; prow[31] = 0;
            }
            #pragma unroll
            for (int mt = 0; mt < 2; ++mt)
            #pragma unroll
            for (int nt = 0; nt < 2; ++nt) {
                short8 a  = *(const short8*)&pb[(mt * 16 + r) * 32 + 8 * g];
                short8 bb = *(const short8*)&VT[head * 1024 + (nt * 16 + r) * 32 + 8 * g];
                f32x4 acc = {0.f, 0.f, 0.f, 0.f};
                acc = __builtin_amdgcn_mfma_f32_16x16x32_bf16(a, bb, acc, 0, 0, 0);
                int vj = nt * 16 + r;
                if (vj < 20) {
                    #pragma unroll
                    for (int j = 0; j < 4; ++j)
                        ctx[(mt * 16 + 4 * g + j) * XS + head * 20 + vj] = f2bf(acc[j]);
                }
            }
        }
    }
    __syncthreads();

    // ---- pooling: tanh(ctx @ Wp + bp) . qv, atomic per-row reduce ----
    const ushort* wp = wt_wp + (size_t)p * NWP * KP;
    for (int tile = wave; tile < 26; tile += 8) {      // 13 nt x 2 mt
        int nt = tile >> 1, mt = tile & 1;
        f32x4 acc = {0.f, 0.f, 0.f, 0.f};
        const ushort* wrow = wp + (size_t)(nt * 16 + r) * KP;
        const ushort* crow = &ctx[(mt * 16 + r) * XS];
        #pragma unroll
        for (int ks = 0; ks < 10; ++ks) {
            short8 a  = *(const short8*)(crow + 32 * ks + 8 * g);
            short8 bb = *(const short8*)(wrow + 32 * ks + 8 * g);
            acc = __builtin_amdgcn_mfma_f32_16x16x32_bf16(a, bb, acc, 0, 0, 0);
        }
        int ai = nt * 16 + r;
        if (ai < 200) {
            float bpv = bp[p * 200 + ai];
            float qvv = qv[p * 200 + ai];
            #pragma unroll
            for (int j = 0; j < 4; ++j) {
                int row = mt * 16 + 4 * g + j;
                atomicAdd(&SL[row], tanhf(acc[j] + bpv) * qvv);
            }
        }
    }
    __syncthreads();
    if (tid == 0) {
        float mx = -1e30f;
        for (int l = 0; l < 30; ++l) mx = fmaxf(mx, SL[l]);
        float s = 0.f;
        for (int l = 0; l < 30; ++l) { float e = __expf(SL[l] - mx); SL[l] = e; s += e; }
        float inv = 1.0f / s;
        for (int l = 0; l < 30; ++l) SL[l] *= inv;
    }
    __syncthreads();
    for (int c = tid; c < 300; c += 512) {
        float o = 0.f;
        for (int l = 0; l < 30; ++l) o = fmaf(SL[l], bf2f(ctx[l * XS + c]), o);
        out[((size_t)b * P + p) * 300 + c] = o;
    }
}

// ---------- user encoder, L=50 (M padded to 64), heads sequential ----------
__global__ __launch_bounds__(512, 1)
void encode_user(const float* __restrict__ news_enc, const ushort* __restrict__ wt_qkv,
                 const ushort* __restrict__ wt_wp, const float* __restrict__ bp,
                 const float* __restrict__ qv, float* __restrict__ user_rep)
{
    __shared__ ushort Xb[64 * XS];    // 41,984 B
    __shared__ ushort Cb[64 * XS];    // 41,984 B
    __shared__ ushort Qh[64 * 32];    // 4,096 B
    __shared__ ushort Kh[64 * 32];
    __shared__ ushort VTh[32 * 64];   // [vj][m]
    __shared__ float  SC[64 * 64];    // 16,384 B
    __shared__ ushort Pb[64 * 64];    // 8,192 B
    __shared__ float  SL[64];
    // total 121,088 B

    const int tid  = threadIdx.x;
    const int wave = tid >> 6;
    const int lane = tid & 63;
    const int r = lane & 15, g = lane >> 4;
    const int b = blockIdx.x;

    for (int i = tid; i < 64 * XS; i += 512) { Xb[i] = 0; Cb[i] = 0; }
    for (int i = tid; i < 64 * 32; i += 512) { Qh[i] = 0; Kh[i] = 0; }
    for (int i = tid; i < 32 * 64; i += 512) VTh[i] = 0;
    for (int i = tid; i < 64 * 64; i += 512) Pb[i] = 0;
    if (tid < 64) SL[tid] = 0.f;
    __syncthreads();

    for (int i = tid; i < 50 * 300; i += 512) {
        int l = i / 300, d = i - l * 300;
        Xb[l * XS + d] = f2bf(news_enc[((size_t)b * 50 + l) * 300 + d]);
    }
    __syncthreads();

    for (int h = 0; h < 15; ++h) {
        // per-head QKV: 3 segs x (2 nt x 4 mt)
        const int nt = wave >> 2, mt = wave & 3;
        for (int seg = 0; seg < 3; ++seg) {
            f32x4 acc = {0.f, 0.f, 0.f, 0.f};
            int n = seg * 300 + h * 20 + nt * 16 + r;
            const ushort* wrow = wt_qkv + (size_t)n * KP;
            const ushort* xrow = &Xb[(mt * 16 + r) * XS];
            #pragma unroll
            for (int ks = 0; ks < 10; ++ks) {
                short8 a  = *(const short8*)(xrow + 32 * ks + 8 * g);
                short8 bb = *(const short8*)(wrow + 32 * ks + 8 * g);
                acc = __builtin_amdgcn_mfma_f32_16x16x32_bf16(a, bb, acc, 0, 0, 0);
            }
            int c = nt * 16 + r;
            if (c < 20) {
                #pragma unroll
                for (int j = 0; j < 4; ++j) {
                    int row = mt * 16 + 4 * g + j;
                    ushort v = f2bf(acc[j]);
                    if (seg == 0)      Qh[row * 32 + c] = v;
                    else if (seg == 1) Kh[row * 32 + c] = v;
                    else               VTh[c * 64 + row] = v;
                }
            }
        }
        __syncthreads();
        // scores: 4x4 tiles, K=32 (padded 20)
        for (int it = 0; it < 2; ++it) {
            int tile = wave + 8 * it;
            int smt = tile & 3, snt = tile >> 2;
            short8 a  = *(const short8*)&Qh[(smt * 16 + r) * 32 + 8 * g];
            short8 bb = *(const short8*)&Kh[(snt * 16 + r) * 32 + 8 * g];
            f32x4 acc = {0.f, 0.f, 0.f, 0.f};
            acc = __builtin_amdgcn_mfma_f32_16x16x32_bf16(a, bb, acc, 0, 0, 0);
            #pragma unroll
            for (int j = 0; j < 4; ++j)
                SC[(smt * 16 + 4 * g + j) * 64 + snt * 16 + r] = acc[j] * SCALE;
        }
        __syncthreads();
        if (tid < 50) {
            float* row = &SC[tid * 64];
            float mx = -1e30f;
            for (int m = 0; m < 50; ++m) mx = fmaxf(mx, row[m]);
            float sum = 0.f;
            for (int m = 0; m < 50; ++m) { float e = __expf(row[m] - mx); row[m] = e; sum += e; }
            float inv = 1.0f / sum;
            ushort* prow = &Pb[tid * 64];
            for (int m = 0; m < 64; ++m) prow[m] = (m < 50) ? f2bf(row[m] * inv) : (ushort)0;
        }
        __syncthreads();
        // ctx: 4 mt x 2 nt tiles, K=64
        {
            int cmt = wave & 3, cnt = wave >> 2;
            f32x4 acc = {0.f, 0.f, 0.f, 0.f};
            #pragma unroll
            for (int ks = 0; ks < 2; ++ks) {
                short8 a  = *(const short8*)&Pb[(cmt * 16 + r) * 64 + 32 * ks + 8 * g];
                short8 bb = *(const short8*)&VTh[(cnt * 16 + r) * 64 + 32 * ks + 8 * g];
                acc = __builtin_amdgcn_mfma_f32_16x16x32_bf16(a, bb, acc, 0, 0, 0);
            }
            int vj = cnt * 16 + r;
            if (vj < 20) {
                #pragma unroll
                for (int j = 0; j < 4; ++j)
                    Cb[(cmt * 16 + 4 * g + j) * XS + h * 20 + vj] = f2bf(acc[j]);
            }
        }
        __syncthreads();
    }

    // pooling: 13 nt x 4 mt = 52 tiles
    for (int tile = wave; tile < 52; tile += 8) {
        int nt = tile >> 2, mt = tile & 3;
        f32x4 acc = {0.f, 0.f, 0.f, 0.f};
        const ushort* wrow = wt_wp + (size_t)(nt * 16 + r) * KP;
        const ushort* crow = &Cb[(mt * 16 + r) * XS];
        #pragma unroll
        for (int ks = 0; ks < 10; ++ks) {
            short8 a  = *(const short8*)(crow + 32 * ks + 8 * g);
            short8 bb = *(const short8*)(wrow + 32 * ks + 8 * g);
            acc = __builtin_amdgcn_mfma_f32_16x16x32_bf16(a, bb, acc, 0, 0, 0);
        }
        int ai = nt * 16 + r;
        if (ai < 200) {
            float bpv = bp[ai], qvv = qv[ai];
            #pragma unroll
            for (int j = 0; j < 4; ++j)
                atomicAdd(&SL[mt * 16 + 4 * g + j], tanhf(acc[j] + bpv) * qvv);
        }
    }
    __syncthreads();
    if (tid == 0) {
        float mx = -1e30f;
        for (int l = 0; l < 50; ++l) mx = fmaxf(mx, SL[l]);
        float s = 0.f;
        for (int l = 0; l < 50; ++l) { float e = __expf(SL[l] - mx); SL[l] = e; s += e; }
        float inv = 1.0f / s;
        for (int l = 0; l < 50; ++l) SL[l] *= inv;
    }
    __syncthreads();
    for (int c = tid; c < 300; c += 512) {
        float o = 0.f;
        for (int l = 0; l < 50; ++l) o = fmaf(SL[l], bf2f(Cb[l * XS + c]), o);
        user_rep[(size_t)b * 300 + c] = o;
    }
}

// ---------- final scoring ----------
__global__ __launch_bounds__(320)
void score_kernel(const float* __restrict__ user_rep, const float* __restrict__ cand_enc,
                  float* __restrict__ out)
{
    __shared__ float sc[NCAND];
    int b = blockIdx.x;
    int w = threadIdx.x >> 6;
    int lane = threadIdx.x & 63;
    float partial = 0.f;
    for (int d = lane; d < 300; d += 64)
        partial = fmaf(user_rep[b * 300 + d], cand_enc[((size_t)b * NCAND + w) * 300 + d], partial);
    for (int off = 32; off > 0; off >>= 1)
        partial += __shfl_down(partial, off, 64);
    if (lane == 0) sc[w] = partial;
    __syncthreads();
    if (threadIdx.x == 0) {
        float mx = -1e30f;
        for (int c = 0; c < NCAND; ++c) mx = fmaxf(mx, sc[c]);
        float s = 0.f; float e[NCAND];
        for (int c = 0; c < NCAND; ++c) { e[c] = __expf(sc[c] - mx); s += e[c]; }
        float inv = 1.0f / s;
        for (int c = 0; c < NCAND; ++c) out[b * NCAND + c] = e[c] * inv;
    }
}

extern "C" void kernel_launch(void* const* d_in, const int* in_sizes, int n_in,
                              void* d_out, int out_size, void* d_ws, size_t ws_size,
                              hipStream_t stream) {
    const int*   news_input = (const int*)d_in[0];
    const int*   candidates = (const int*)d_in[1];
    const float* emb        = (const float*)d_in[2];
    const float* his_Wq  = (const float*)d_in[3];
    const float* his_Wk  = (const float*)d_in[4];
    const float* his_Wv  = (const float*)d_in[5];
    const float* his_Wp  = (const float*)d_in[6];
    const float* his_bp  = (const float*)d_in[7];
    const float* his_qv  = (const float*)d_in[8];
    const float* cand_Wq = (const float*)d_in[9];
    const float* cand_Wk = (const float*)d_in[10];
    const float* cand_Wv = (const float*)d_in[11];
    const float* cand_Wp = (const float*)d_in[12];
    const float* cand_bp = (const float*)d_in[13];
    const float* cand_qv = (const float*)d_in[14];
    const float* usr_Wq  = (const float*)d_in[15];
    const float* usr_Wk  = (const float*)d_in[16];
    const float* usr_Wv  = (const float*)d_in[17];
    const float* usr_Wp  = (const float*)d_in[18];
    const float* usr_bp  = (const float*)d_in[19];
    const float* usr_qv  = (const float*)d_in[20];
    float* out = (float*)d_out;

    char* ws = (char*)d_ws;
    float* news_enc = (float*)ws;                 ws += (size_t)BATCH * NHIS * 300 * 4;   // 7,680,000
    float* cand_enc = (float*)ws;                 ws += (size_t)BATCH * NCAND * 300 * 4;  //   768,000
    float* user_rep = (float*)ws;                 ws += (size_t)BATCH * 300 * 4;          //   153,600
    ushort* his_qkvT  = (ushort*)ws;              ws += (size_t)NHIS * NQKV * KP * 2;
    ushort* his_wpT   = (ushort*)ws;              ws += (size_t)NHIS * NWP  * KP * 2;
    ushort* cand_qkvT = (ushort*)ws;              ws += (size_t)NCAND * NQKV * KP * 2;
    ushort* cand_wpT  = (ushort*)ws;              ws += (size_t)NCAND * NWP  * KP * 2;
    ushort* usr_qkvT  = (ushort*)ws;              ws += (size_t)NQKV * KP * 2;
    ushort* usr_wpT   = (ushort*)ws;              ws += (size_t)NWP  * KP * 2;

    auto blocks = [](size_t total) { return (int)((total + 255) / 256); };

    prep_qkv<<<blocks((size_t)NHIS  * NQKV * KP), 256, 0, stream>>>(his_Wq,  his_Wk,  his_Wv,  his_qkvT,  NHIS);
    prep_qkv<<<blocks((size_t)NCAND * NQKV * KP), 256, 0, stream>>>(cand_Wq, cand_Wk, cand_Wv, cand_qkvT, NCAND);
    prep_qkv<<<blocks((size_t)1     * NQKV * KP), 256, 0, stream>>>(usr_Wq,  usr_Wk,  usr_Wv,  usr_qkvT,  1);
    prep_wp <<<blocks((size_t)NHIS  * NWP  * KP), 256, 0, stream>>>(his_Wp,  his_wpT,  NHIS);
    prep_wp <<<blocks((size_t)NCAND * NWP  * KP), 256, 0, stream>>>(cand_Wp, cand_wpT, NCAND);
    prep_wp <<<blocks((size_t)1     * NWP  * KP), 256, 0, stream>>>(usr_Wp,  usr_wpT,  1);

    encode30<<<NHIS * BATCH, 512, 0, stream>>>(emb, news_input, his_qkvT, his_wpT,
                                               his_bp, his_qv, news_enc, NHIS);
    encode30<<<NCAND * BATCH, 512, 0, stream>>>(emb, candidates, cand_qkvT, cand_wpT,
                                                cand_bp, cand_qv, cand_enc, NCAND);
    encode_user<<<BATCH, 512, 0, stream>>>(news_enc, usr_qkvT, usr_wpT, usr_bp, usr_qv, user_rep);
    score_kernel<<<BATCH, 320, 0, stream>>>(user_rep, cand_enc, out);
}

// Round 3
// 1428.173 us; speedup vs baseline: 13.7144x; 1.4049x over previous
//
#include <hip/hip_runtime.h>
#include <math.h>

typedef __attribute__((ext_vector_type(8))) short short8;
typedef __attribute__((ext_vector_type(4))) float f32x4;

union U32S8 { unsigned u[4]; short8 s8; };

#define BATCH 128
#define NHIS  50
#define NCAND 5
#define KP    320   // padded K stride for transposed weights (elems)
#define XS    328   // X/CTX LDS row stride (656B: 164 words % 32 = 4 -> 2-way max)
#define QS    488   // Q/K LDS row stride (976B: 244 % 32 = 20 -> 2-way max)
#define VTS   40    // VT row stride (80B: 20 % 32 -> 2-way max)
#define NQKV  912   // padded N for [Wq|Wk|Wv]
#define NWP   208   // padded N for Wp
#define SCALE 0.22360679774997896f  // 1/sqrt(20)

__device__ __forceinline__ ushort f2bf(float f) {
    union { float f; unsigned u; } v; v.f = f;
    return (ushort)((v.u + 0x7fffu + ((v.u >> 16) & 1u)) >> 16);
}
__device__ __forceinline__ unsigned pack2bf(float lo, float hi) {
    return (unsigned)f2bf(lo) | ((unsigned)f2bf(hi) << 16);
}
__device__ __forceinline__ float bf2f(ushort u) {
    union { float f; unsigned u; } v; v.u = ((unsigned)u) << 16;
    return v.f;
}

// ---------- weight prep: W[k][n] fp32 -> WT[p][n][k] bf16, zero-padded ----------
__global__ void prep_qkv(const float* __restrict__ Wq, const float* __restrict__ Wk,
                         const float* __restrict__ Wv, ushort* __restrict__ dst, int P) {
    size_t i = (size_t)blockIdx.x * 256 + threadIdx.x;
    size_t total = (size_t)P * NQKV * KP;
    if (i >= total) return;
    int k = (int)(i % KP);
    int n = (int)((i / KP) % NQKV);
    int p = (int)(i / ((size_t)KP * NQKV));
    float v = 0.f;
    if (k < 300 && n < 900) {
        const float* W = (n < 300) ? Wq : (n < 600 ? Wk : Wv);
        int nn = n % 300;
        v = W[((size_t)p * 300 + k) * 300 + nn];
    }
    dst[i] = f2bf(v);
}

__global__ void prep_wp(const float* __restrict__ Wp, ushort* __restrict__ dst, int P) {
    size_t i = (size_t)blockIdx.x * 256 + threadIdx.x;
    size_t total = (size_t)P * NWP * KP;
    if (i >= total) return;
    int k = (int)(i % KP);
    int a = (int)((i / KP) % NWP);
    int p = (int)(i / ((size_t)KP * NWP));
    float v = 0.f;
    if (k < 300 && a < 200) v = Wp[((size_t)p * 300 + k) * 200 + a];
    dst[i] = f2bf(v);
}

// ---------- fused MFMA encoder, L=30, register softmax ----------
// MFMA 16x16x32 bf16: A-lane(r=l&15,g=l>>4) holds A[r][8g+i]; B: B[8g+i][r];
// D: reg j = D[4g+j][r].
__global__ __launch_bounds__(512, 1)
void encode30(const float* __restrict__ emb, const int* __restrict__ tokens,
              const ushort* __restrict__ wt_qkv, const ushort* __restrict__ wt_wp,
              const float* __restrict__ bp, const float* __restrict__ qv,
              float* __restrict__ out, int P)
{
    __shared__ ushort Xb[32 * XS];        // 20,992 B; becomes CTX after QKV
    __shared__ ushort Qb[32 * QS];        // 31,232 B  [row][h*32+j] (j<20 valid)
    __shared__ ushort Kb[32 * QS];        // 31,232 B
    __shared__ ushort VT[15 * 32 * VTS];  // 38,400 B  [h][vj][m], m stride 40
    __shared__ float  SL[64];
    __shared__ int    TOK[32];
    // total ~122.4 KB

    const int tid  = threadIdx.x;
    const int wave = tid >> 6;
    const int lane = tid & 63;
    const int r = lane & 15, g = lane >> 4;
    const int p = blockIdx.x / BATCH;     // p-major: co-resident blocks share weights
    const int b = blockIdx.x % BATCH;

    for (int i = tid; i < 32 * XS; i += 512) Xb[i] = 0;
    for (int i = tid; i < 32 * QS; i += 512) { Qb[i] = 0; Kb[i] = 0; }
    for (int i = tid; i < 15 * 32 * VTS; i += 512) VT[i] = 0;
    if (tid < 64) SL[tid] = 0.f;
    if (tid < 30) TOK[tid] = tokens[((size_t)b * P + p) * 30 + tid];
    __syncthreads();

    // gather X -> bf16 (vectorized: 75 float4 per row)
    {
        const float4* emb4 = (const float4*)emb;
        for (int i = tid; i < 30 * 75; i += 512) {
            int l = i / 75, q = i - l * 75;
            float4 v = emb4[(size_t)TOK[l] * 75 + q];
            unsigned w0 = pack2bf(v.x, v.y), w1 = pack2bf(v.z, v.w);
            *(unsigned*)&Xb[l * XS + q * 4]     = w0;
            *(unsigned*)&Xb[l * XS + q * 4 + 2] = w1;
        }
    }
    __syncthreads();

    // ---- QKV: [32 x 320] x [320 x 912], B prefetched to regs, reused over mt ----
    const ushort* wq = wt_qkv + (size_t)p * NQKV * KP;
    for (int nt = wave; nt < 57; nt += 8) {
        const ushort* wrow = wq + (size_t)(nt * 16 + r) * KP + 8 * g;
        short8 breg[10];
        #pragma unroll
        for (int ks = 0; ks < 10; ++ks) breg[ks] = *(const short8*)(wrow + 32 * ks);

        int n = nt * 16 + r;
        int seg = (n >= 600) ? 2 : (n >= 300 ? 1 : 0);
        int nn = n - seg * 300;
        int h = nn / 20, jj = nn - h * 20;

        #pragma unroll
        for (int mt = 0; mt < 2; ++mt) {
            f32x4 acc = {0.f, 0.f, 0.f, 0.f};
            const ushort* xrow = &Xb[(mt * 16 + r) * XS + 8 * g];
            #pragma unroll
            for (int ks = 0; ks < 10; ++ks) {
                short8 a = *(const short8*)(xrow + 32 * ks);
                acc = __builtin_amdgcn_mfma_f32_16x16x32_bf16(a, breg[ks], acc, 0, 0, 0);
            }
            if (n < 900) {
                #pragma unroll
                for (int j = 0; j < 4; ++j) {
                    int row = mt * 16 + 4 * g + j;
                    ushort v = f2bf(acc[j]);
                    if (seg == 0)      Qb[row * QS + h * 32 + jj] = v;
                    else if (seg == 1) Kb[row * QS + h * 32 + jj] = v;
                    else               VT[h * (32 * VTS) + jj * VTS + row] = v;
                }
            }
        }
    }
    __syncthreads();

    // X dead; zero CTX region (pads must be 0 for pooling MFMA)
    for (int i = tid; i < 32 * XS; i += 512) Xb[i] = 0;
    __syncthreads();

    // ---- attention: head per wave, all in registers ----
    ushort* ctx = Xb;
    #pragma unroll
    for (int hp = 0; hp < 2; ++hp) {
        int head = wave + 8 * hp;
        if (head < 15) {
            // S^T = K . Q^T : lane holds S[16lt+r][16mt+4g+j]
            f32x4 s0m0 = {0,0,0,0}, s0m1 = {0,0,0,0}, s1m0 = {0,0,0,0}, s1m1 = {0,0,0,0};
            {
                short8 k0 = *(const short8*)&Kb[(0 * 16 + r) * QS + head * 32 + 8 * g];
                short8 k1 = *(const short8*)&Kb[(1 * 16 + r) * QS + head * 32 + 8 * g];
                short8 q0 = *(const short8*)&Qb[(0 * 16 + r) * QS + head * 32 + 8 * g];
                short8 q1 = *(const short8*)&Qb[(1 * 16 + r) * QS + head * 32 + 8 * g];
                s0m0 = __builtin_amdgcn_mfma_f32_16x16x32_bf16(k0, q0, s0m0, 0, 0, 0);
                s0m1 = __builtin_amdgcn_mfma_f32_16x16x32_bf16(k1, q0, s0m1, 0, 0, 0);
                s1m0 = __builtin_amdgcn_mfma_f32_16x16x32_bf16(k0, q1, s1m0, 0, 0, 0);
                s1m1 = __builtin_amdgcn_mfma_f32_16x16x32_bf16(k1, q1, s1m1, 0, 0, 0);
            }
            // scale + mask cols >=30 (mt=1, 4g+j>=14)
            float mx0 = -1e30f, mx1 = -1e30f;
            #pragma unroll
            for (int j = 0; j < 4; ++j) {
                s0m0[j] *= SCALE; s1m0[j] *= SCALE;
                float v01 = (16 + 4 * g + j < 30) ? s0m1[j] * SCALE : -1e30f;
                float v11 = (16 + 4 * g + j < 30) ? s1m1[j] * SCALE : -1e30f;
                s0m1[j] = v01; s1m1[j] = v11;
                mx0 = fmaxf(mx0, fmaxf(s0m0[j], v01));
                mx1 = fmaxf(mx1, fmaxf(s1m0[j], v11));
            }
            mx0 = fmaxf(mx0, __shfl_xor(mx0, 16, 64));
            mx0 = fmaxf(mx0, __shfl_xor(mx0, 32, 64));
            mx1 = fmaxf(mx1, __shfl_xor(mx1, 16, 64));
            mx1 = fmaxf(mx1, __shfl_xor(mx1, 32, 64));
            float sm0 = 0.f, sm1 = 0.f;
            #pragma unroll
            for (int j = 0; j < 4; ++j) {
                s0m0[j] = __expf(s0m0[j] - mx0); s0m1[j] = __expf(s0m1[j] - mx0);
                s1m0[j] = __expf(s1m0[j] - mx1); s1m1[j] = __expf(s1m1[j] - mx1);
                sm0 += s0m0[j] + s0m1[j];
                sm1 += s1m0[j] + s1m1[j];
            }
            sm0 += __shfl_xor(sm0, 16, 64); sm0 += __shfl_xor(sm0, 32, 64);
            sm1 += __shfl_xor(sm1, 16, 64); sm1 += __shfl_xor(sm1, 32, 64);
            float inv0 = 1.0f / sm0, inv1 = 1.0f / sm1;
            // pack P rows to bf16 pairs: pk[lt][mt][w]
            unsigned pk000 = pack2bf(s0m0[0] * inv0, s0m0[1] * inv0);
            unsigned pk001 = pack2bf(s0m0[2] * inv0, s0m0[3] * inv0);
            unsigned pk010 = pack2bf(s0m1[0] * inv0, s0m1[1] * inv0);
            unsigned pk011 = pack2bf(s0m1[2] * inv0, s0m1[3] * inv0);
            unsigned pk100 = pack2bf(s1m0[0] * inv1, s1m0[1] * inv1);
            unsigned pk101 = pack2bf(s1m0[2] * inv1, s1m0[3] * inv1);
            unsigned pk110 = pack2bf(s1m1[0] * inv1, s1m1[1] * inv1);
            unsigned pk111 = pack2bf(s1m1[2] * inv1, s1m1[3] * inv1);

            const int sA = r + 16 * (2 * (g & 1));
            const int sB = sA + 16;
            const bool hi = (g >> 1) != 0;
            #pragma unroll
            for (int lt = 0; lt < 2; ++lt) {
                unsigned q00 = lt ? pk100 : pk000, q01 = lt ? pk101 : pk001;
                unsigned q10 = lt ? pk110 : pk010, q11 = lt ? pk111 : pk011;
                unsigned a0 = __shfl((int)q00, sA, 64), a1 = __shfl((int)q01, sA, 64);
                unsigned a2 = __shfl((int)q10, sA, 64), a3 = __shfl((int)q11, sA, 64);
                unsigned b0 = __shfl((int)q00, sB, 64), b1 = __shfl((int)q01, sB, 64);
                unsigned b2 = __shfl((int)q10, sB, 64), b3 = __shfl((int)q11, sB, 64);
                U32S8 pf;
                pf.u[0] = hi ? a2 : a0;
                pf.u[1] = hi ? a3 : a1;
                pf.u[2] = hi ? b2 : b0;
                pf.u[3] = hi ? b3 : b1;
                int lrow = lt * 16 + r;
                #pragma unroll
                for (int nt = 0; nt < 2; ++nt) {
                    short8 vf = *(const short8*)&VT[head * (32 * VTS) + (nt * 16 + r) * VTS + 8 * g];
                    f32x4 c = {0.f, 0.f, 0.f, 0.f};
                    c = __builtin_amdgcn_mfma_f32_16x16x32_bf16(vf, pf.s8, c, 0, 0, 0);
                    if (lrow < 30) {
                        #pragma unroll
                        for (int j = 0; j < 4; ++j) {
                            int vj = nt * 16 + 4 * g + j;
                            if (vj < 20)
                                ctx[lrow * XS + head * 20 + vj] = f2bf(c[j]);
                        }
                    }
                }
            }
        }
    }
    __syncthreads();

    // ---- pooling: tanh(ctx @ Wp + bp) . qv ----
    const ushort* wp = wt_wp + (size_t)p * NWP * KP;
    for (int nt = wave; nt < 13; nt += 8) {
        const ushort* wrow = wp + (size_t)(nt * 16 + r) * KP + 8 * g;
        short8 breg[10];
        #pragma unroll
        for (int ks = 0; ks < 10; ++ks) breg[ks] = *(const short8*)(wrow + 32 * ks);
        int ai = nt * 16 + r;
        float bpv = (ai < 200) ? bp[p * 200 + ai] : 0.f;
        float qvv = (ai < 200) ? qv[p * 200 + ai] : 0.f;
        #pragma unroll
        for (int mt = 0; mt < 2; ++mt) {
            f32x4 acc = {0.f, 0.f, 0.f, 0.f};
            const ushort* crow = &ctx[(mt * 16 + r) * XS + 8 * g];
            #pragma unroll
            for (int ks = 0; ks < 10; ++ks) {
                short8 a = *(const short8*)(crow + 32 * ks);
                acc = __builtin_amdgcn_mfma_f32_16x16x32_bf16(a, breg[ks], acc, 0, 0, 0);
            }
            if (ai < 200) {
                #pragma unroll
                for (int j = 0; j < 4; ++j)
                    atomicAdd(&SL[mt * 16 + 4 * g + j], tanhf(acc[j] + bpv) * qvv);
            }
        }
    }
    __syncthreads();
    if (tid == 0) {
        float mx = -1e30f;
        for (int l = 0; l < 30; ++l) mx = fmaxf(mx, SL[l]);
        float s = 0.f;
        for (int l = 0; l < 30; ++l) { float e = __expf(SL[l] - mx); SL[l] = e; s += e; }
        float inv = 1.0f / s;
        for (int l = 0; l < 30; ++l) SL[l] *= inv;
    }
    __syncthreads();
    for (int c = tid; c < 300; c += 512) {
        float o = 0.f;
        for (int l = 0; l < 30; ++l) o = fmaf(SL[l], bf2f(ctx[l * XS + c]), o);
        out[((size_t)b * P + p) * 300 + c] = o;
    }
}

// ---------- user encoder, L=50 (unchanged from R2: small share of runtime) ----------
__global__ __launch_bounds__(512, 1)
void encode_user(const float* __restrict__ news_enc, const ushort* __restrict__ wt_qkv,
                 const ushort* __restrict__ wt_wp, const float* __restrict__ bp,
                 const float* __restrict__ qv, float* __restrict__ user_rep)
{
    __shared__ ushort Xb[64 * XS];
    __shared__ ushort Cb[64 * XS];
    __shared__ ushort Qh[64 * 32];
    __shared__ ushort Kh[64 * 32];
    __shared__ ushort VTh[32 * 64];
    __shared__ float  SC[64 * 64];
    __shared__ ushort Pb[64 * 64];
    __shared__ float  SL[64];

    const int tid  = threadIdx.x;
    const int wave = tid >> 6;
    const int lane = tid & 63;
    const int r = lane & 15, g = lane >> 4;
    const int b = blockIdx.x;

    for (int i = tid; i < 64 * XS; i += 512) { Xb[i] = 0; Cb[i] = 0; }
    for (int i = tid; i < 64 * 32; i += 512) { Qh[i] = 0; Kh[i] = 0; }
    for (int i = tid; i < 32 * 64; i += 512) VTh[i] = 0;
    for (int i = tid; i < 64 * 64; i += 512) Pb[i] = 0;
    if (tid < 64) SL[tid] = 0.f;
    __syncthreads();

    for (int i = tid; i < 50 * 300; i += 512) {
        int l = i / 300, d = i - l * 300;
        Xb[l * XS + d] = f2bf(news_enc[((size_t)b * 50 + l) * 300 + d]);
    }
    __syncthreads();

    for (int h = 0; h < 15; ++h) {
        const int nt = wave >> 2, mt = wave & 3;
        for (int seg = 0; seg < 3; ++seg) {
            f32x4 acc = {0.f, 0.f, 0.f, 0.f};
            int n = seg * 300 + h * 20 + nt * 16 + r;
            const ushort* wrow = wt_qkv + (size_t)n * KP + 8 * g;
            short8 breg[10];
            #pragma unroll
            for (int ks = 0; ks < 10; ++ks) breg[ks] = *(const short8*)(wrow + 32 * ks);
            const ushort* xrow = &Xb[(mt * 16 + r) * XS + 8 * g];
            #pragma unroll
            for (int ks = 0; ks < 10; ++ks) {
                short8 a = *(const short8*)(xrow + 32 * ks);
                acc = __builtin_amdgcn_mfma_f32_16x16x32_bf16(a, breg[ks], acc, 0, 0, 0);
            }
            int c = nt * 16 + r;
            if (c < 20) {
                #pragma unroll
                for (int j = 0; j < 4; ++j) {
                    int row = mt * 16 + 4 * g + j;
                    ushort v = f2bf(acc[j]);
                    if (seg == 0)      Qh[row * 32 + c] = v;
                    else if (seg == 1) Kh[row * 32 + c] = v;
                    else               VTh[c * 64 + row] = v;
                }
            }
        }
        __syncthreads();
        for (int it = 0; it < 2; ++it) {
            int tile = wave + 8 * it;
            int smt = tile & 3, snt = tile >> 2;
            short8 a  = *(const short8*)&Qh[(smt * 16 + r) * 32 + 8 * g];
            short8 bb = *(const short8*)&Kh[(snt * 16 + r) * 32 + 8 * g];
            f32x4 acc = {0.f, 0.f, 0.f, 0.f};
            acc = __builtin_amdgcn_mfma_f32_16x16x32_bf16(a, bb, acc, 0, 0, 0);
            #pragma unroll
            for (int j = 0; j < 4; ++j)
                SC[(smt * 16 + 4 * g + j) * 64 + snt * 16 + r] = acc[j] * SCALE;
        }
        __syncthreads();
        if (tid < 50) {
            float* row = &SC[tid * 64];
            float mx = -1e30f;
            for (int m = 0; m < 50; ++m) mx = fmaxf(mx, row[m]);
            float sum = 0.f;
            for (int m = 0; m < 50; ++m) { float e = __expf(row[m] - mx); row[m] = e; sum += e; }
            float inv = 1.0f / sum;
            ushort* prow = &Pb[tid * 64];
            for (int m = 0; m < 64; ++m) prow[m] = (m < 50) ? f2bf(row[m] * inv) : (ushort)0;
        }
        __syncthreads();
        {
            int cmt = wave & 3, cnt = wave >> 2;
            f32x4 acc = {0.f, 0.f, 0.f, 0.f};
            #pragma unroll
            for (int ks = 0; ks < 2; ++ks) {
                short8 a  = *(const short8*)&Pb[(cmt * 16 + r) * 64 + 32 * ks + 8 * g];
                short8 bb = *(const short8*)&VTh[(cnt * 16 + r) * 64 + 32 * ks + 8 * g];
                acc = __builtin_amdgcn_mfma_f32_16x16x32_bf16(a, bb, acc, 0, 0, 0);
            }
            int vj = cnt * 16 + r;
            if (vj < 20) {
                #pragma unroll
                for (int j = 0; j < 4; ++j)
                    Cb[(cmt * 16 + 4 * g + j) * XS + h * 20 + vj] = f2bf(acc[j]);
            }
        }
        __syncthreads();
    }

    for (int tile = wave; tile < 52; tile += 8) {
        int nt = tile >> 2, mt = tile & 3;
        f32x4 acc = {0.f, 0.f, 0.f, 0.f};
        const ushort* wrow = wt_wp + (size_t)(nt * 16 + r) * KP + 8 * g;
        short8 breg[10];
        #pragma unroll
        for (int ks = 0; ks < 10; ++ks) breg[ks] = *(const short8*)(wrow + 32 * ks);
        const ushort* crow = &Cb[(mt * 16 + r) * XS + 8 * g];
        #pragma unroll
        for (int ks = 0; ks < 10; ++ks) {
            short8 a = *(const short8*)(crow + 32 * ks);
            acc = __builtin_amdgcn_mfma_f32_16x16x32_bf16(a, breg[ks], acc, 0, 0, 0);
        }
        int ai = nt * 16 + r;
        if (ai < 200) {
            float bpv = bp[ai], qvv = qv[ai];
            #pragma unroll
            for (int j = 0; j < 4; ++j)
                atomicAdd(&SL[mt * 16 + 4 * g + j], tanhf(acc[j] + bpv) * qvv);
        }
    }
    __syncthreads();
    if (tid == 0) {
        float mx = -1e30f;
        for (int l = 0; l < 50; ++l) mx = fmaxf(mx, SL[l]);
        float s = 0.f;
        for (int l = 0; l < 50; ++l) { float e = __expf(SL[l] - mx); SL[l] = e; s += e; }
        float inv = 1.0f / s;
        for (int l = 0; l < 50; ++l) SL[l] *= inv;
    }
    __syncthreads();
    for (int c = tid; c < 300; c += 512) {
        float o = 0.f;
        for (int l = 0; l < 50; ++l) o = fmaf(SL[l], bf2f(Cb[l * XS + c]), o);
        user_rep[(size_t)b * 300 + c] = o;
    }
}

// ---------- final scoring ----------
__global__ __launch_bounds__(320)
void score_kernel(const float* __restrict__ user_rep, const float* __restrict__ cand_enc,
                  float* __restrict__ out)
{
    __shared__ float sc[NCAND];
    int b = blockIdx.x;
    int w = threadIdx.x >> 6;
    int lane = threadIdx.x & 63;
    float partial = 0.f;
    for (int d = lane; d < 300; d += 64)
        partial = fmaf(user_rep[b * 300 + d], cand_enc[((size_t)b * NCAND + w) * 300 + d], partial);
    for (int off = 32; off > 0; off >>= 1)
        partial += __shfl_down(partial, off, 64);
    if (lane == 0) sc[w] = partial;
    __syncthreads();
    if (threadIdx.x == 0) {
        float mx = -1e30f;
        for (int c = 0; c < NCAND; ++c) mx = fmaxf(mx, sc[c]);
        float s = 0.f; float e[NCAND];
        for (int c = 0; c < NCAND; ++c) { e[c] = __expf(sc[c] - mx); s += e[c]; }
        float inv = 1.0f / s;
        for (int c = 0; c < NCAND; ++c) out[b * NCAND + c] = e[c] * inv;
    }
}

extern "C" void kernel_launch(void* const* d_in, const int* in_sizes, int n_in,
                              void* d_out, int out_size, void* d_ws, size_t ws_size,
                              hipStream_t stream) {
    const int*   news_input = (const int*)d_in[0];
    const int*   candidates = (const int*)d_in[1];
    const float* emb        = (const float*)d_in[2];
    const float* his_Wq  = (const float*)d_in[3];
    const float* his_Wk  = (const float*)d_in[4];
    const float* his_Wv  = (const float*)d_in[5];
    const float* his_Wp  = (const float*)d_in[6];
    const float* his_bp  = (const float*)d_in[7];
    const float* his_qv  = (const float*)d_in[8];
    const float* cand_Wq = (const float*)d_in[9];
    const float* cand_Wk = (const float*)d_in[10];
    const float* cand_Wv = (const float*)d_in[11];
    const float* cand_Wp = (const float*)d_in[12];
    const float* cand_bp = (const float*)d_in[13];
    const float* cand_qv = (const float*)d_in[14];
    const float* usr_Wq  = (const float*)d_in[15];
    const float* usr_Wk  = (const float*)d_in[16];
    const float* usr_Wv  = (const float*)d_in[17];
    const float* usr_Wp  = (const float*)d_in[18];
    const float* usr_bp  = (const float*)d_in[19];
    const float* usr_qv  = (const float*)d_in[20];
    float* out = (float*)d_out;

    char* ws = (char*)d_ws;
    float* news_enc = (float*)ws;                 ws += (size_t)BATCH * NHIS * 300 * 4;
    float* cand_enc = (float*)ws;                 ws += (size_t)BATCH * NCAND * 300 * 4;
    float* user_rep = (float*)ws;                 ws += (size_t)BATCH * 300 * 4;
    ushort* his_qkvT  = (ushort*)ws;              ws += (size_t)NHIS * NQKV * KP * 2;
    ushort* his_wpT   = (ushort*)ws;              ws += (size_t)NHIS * NWP  * KP * 2;
    ushort* cand_qkvT = (ushort*)ws;              ws += (size_t)NCAND * NQKV * KP * 2;
    ushort* cand_wpT  = (ushort*)ws;              ws += (size_t)NCAND * NWP  * KP * 2;
    ushort* usr_qkvT  = (ushort*)ws;              ws += (size_t)NQKV * KP * 2;
    ushort* usr_wpT   = (ushort*)ws;              ws += (size_t)NWP  * KP * 2;

    auto blocks = [](size_t total) { return (int)((total + 255) / 256); };

    prep_qkv<<<blocks((size_t)NHIS  * NQKV * KP), 256, 0, stream>>>(his_Wq,  his_Wk,  his_Wv,  his_qkvT,  NHIS);
    prep_qkv<<<blocks((size_t)NCAND * NQKV * KP), 256, 0, stream>>>(cand_Wq, cand_Wk, cand_Wv, cand_qkvT, NCAND);
    prep_qkv<<<blocks((size_t)1     * NQKV * KP), 256, 0, stream>>>(usr_Wq,  usr_Wk,  usr_Wv,  usr_qkvT,  1);
    prep_wp <<<blocks((size_t)NHIS  * NWP  * KP), 256, 0, stream>>>(his_Wp,  his_wpT,  NHIS);
    prep_wp <<<blocks((size_t)NCAND * NWP  * KP), 256, 0, stream>>>(cand_Wp, cand_wpT, NCAND);
    prep_wp <<<blocks((size_t)1     * NWP  * KP), 256, 0, stream>>>(usr_Wp,  usr_wpT,  1);

    encode30<<<NHIS * BATCH, 512, 0, stream>>>(emb, news_input, his_qkvT, his_wpT,
                                               his_bp, his_qv, news_enc, NHIS);
    encode30<<<NCAND * BATCH, 512, 0, stream>>>(emb, candidates, cand_qkvT, cand_wpT,
                                                cand_bp, cand_qv, cand_enc, NCAND);
    encode_user<<<BATCH, 512, 0, stream>>>(news_enc, usr_qkvT, usr_wpT, usr_bp, usr_qv, user_rep);
    score_kernel<<<BATCH, 320, 0, stream>>>(user_rep, cand_enc, out);
}